// Round 7
// baseline (54.233 us; speedup 1.0000x reference)
//
#include <hip/hip_runtime.h>

#define NUM_CLASSES 100
#define QUEUE_SIZE  256
#define FEATURE_DIM 1024
#define BATCH       4096
#define TOTAL_ROWS  (NUM_CLASSES * QUEUE_SIZE)   // 25600
#define EPS         1e-12f

typedef float f32x4 __attribute__((ext_vector_type(4)));

// ---------------------------------------------------------------------------
// Kernel 1: direct inverse-map construction. One block per class.
// Wave 0 ballot-scans labels[0..4096) building the ordered occurrence list
// occ[k] = batch index of the k-th occurrence of class c. Then thread s
// (s = slot index 0..255) computes in closed form which occurrence lands
// last on slot s:
//   k0 = (s - ptr[c]) mod 256 ; valid iff k0 < cnt
//   k  = k0 + 256*floor((cnt-1-k0)/256)   (last write wins, serial FIFO)
//   inv[c*256+s] = occ[k]  (or -1 if slot untouched)
// Every inv entry written exactly once: no memset, no atomics.
// ---------------------------------------------------------------------------
__global__ __launch_bounds__(256) void slots_direct_kernel(
    const int* __restrict__ labels,
    const int* __restrict__ queue_ptr,
    int* __restrict__ inv)
{
    __shared__ int occ[BATCH];     // 16 KB
    __shared__ int s_cnt;

    const int c    = blockIdx.x;
    const int tid  = threadIdx.x;
    const int lane = tid & 63;

    if (tid < 64) {   // wave 0 builds the ordered occurrence list
        int base = 0;
        const unsigned long long lt = (1ULL << lane) - 1ULL;
        #pragma unroll 4
        for (int i = 0; i < BATCH / 64; ++i) {
            const int b = i * 64 + lane;
            const bool m = (labels[b] == c);
            const unsigned long long mask = __ballot(m);
            if (m) occ[base + __popcll(mask & lt)] = b;
            base += __popcll(mask);
        }
        if (lane == 0) s_cnt = base;
    }
    __syncthreads();

    const int cnt = s_cnt;
    const int p   = queue_ptr[c] & (QUEUE_SIZE - 1);
    const int s   = tid;                       // slot index
    const int k0  = (s - p) & (QUEUE_SIZE - 1);
    int b = -1;
    if (k0 < cnt) {
        const int k = k0 + (((cnt - 1 - k0) >> 8) << 8);   // last wrap wins
        b = occ[k];
    }
    inv[c * QUEUE_SIZE + s] = b;
}

// ---------------------------------------------------------------------------
// Kernel 2: fused writer, one wave per row. Plain cached loads AND stores —
// the full working set (queue+emb+out = 227 MB) fits the 256 MB Infinity
// Cache, so write-back caching can absorb the write stream across replays.
// Wave-uniform branch, shfl-only reduction, no LDS, no __syncthreads.
// ---------------------------------------------------------------------------
__global__ __launch_bounds__(256) void fused_write_kernel(
    const float* __restrict__ queue,
    const float* __restrict__ emb,
    const int* __restrict__ inv,
    float* __restrict__ out)
{
    const int tid  = threadIdx.x;
    const int lane = tid & 63;
    const int wave = tid >> 6;
    const int row  = blockIdx.x * 4 + wave;
    const long base = (long)row * FEATURE_DIM;

    const int b = inv[row];   // wave-uniform
    f32x4* dst = reinterpret_cast<f32x4*>(out + base);

    if (b < 0) {
        const f32x4* src = reinterpret_cast<const f32x4*>(queue + base);
        f32x4 v0 = src[lane];
        f32x4 v1 = src[lane + 64];
        f32x4 v2 = src[lane + 128];
        f32x4 v3 = src[lane + 192];
        dst[lane]       = v0;
        dst[lane + 64]  = v1;
        dst[lane + 128] = v2;
        dst[lane + 192] = v3;
    } else {
        const f32x4* src = reinterpret_cast<const f32x4*>(emb + (long)b * FEATURE_DIM);
        f32x4 v0 = src[lane];
        f32x4 v1 = src[lane + 64];
        f32x4 v2 = src[lane + 128];
        f32x4 v3 = src[lane + 192];

        float ss = v0.x*v0.x + v0.y*v0.y + v0.z*v0.z + v0.w*v0.w
                 + v1.x*v1.x + v1.y*v1.y + v1.z*v1.z + v1.w*v1.w
                 + v2.x*v2.x + v2.y*v2.y + v2.z*v2.z + v2.w*v2.w
                 + v3.x*v3.x + v3.y*v3.y + v3.z*v3.z + v3.w*v3.w;
        #pragma unroll
        for (int off = 32; off; off >>= 1) {
            ss += __shfl_xor(ss, off, 64);
        }
        const float sc = 1.0f / fmaxf(sqrtf(ss), EPS);

        dst[lane]       = v0 * sc;
        dst[lane + 64]  = v1 * sc;
        dst[lane + 128] = v2 * sc;
        dst[lane + 192] = v3 * sc;
    }
}

// ---------------------------------------------------------------------------
extern "C" void kernel_launch(void* const* d_in, const int* in_sizes, int n_in,
                              void* d_out, int out_size, void* d_ws, size_t ws_size,
                              hipStream_t stream)
{
    const float* embeddings = (const float*)d_in[0];   // (4096, 1024) f32
    const int*   labels     = (const int*)d_in[1];     // (4096,) int
    const float* queue      = (const float*)d_in[2];   // (100, 256, 1024) f32
    const int*   queue_ptr  = (const int*)d_in[3];     // (100,) int

    float* out = (float*)d_out;                        // (100, 256, 1024) f32
    int*   inv = (int*)d_ws;                           // 25600 ints scratch

    // 1) direct inverse map: one block per class, no memset, no atomics
    slots_direct_kernel<<<NUM_CLASSES, 256, 0, stream>>>(labels, queue_ptr, inv);

    // 2) fused copy/normalize-scatter: one wave per row, cached loads+stores
    fused_write_kernel<<<TOTAL_ROWS / 4, 256, 0, stream>>>(
        queue, embeddings, inv, out);
}

// Round 8
// 40.977 us; speedup vs baseline: 1.3235x; 1.3235x over previous
//
#include <hip/hip_runtime.h>

#define NUM_CLASSES 100
#define QUEUE_SIZE  256
#define FEATURE_DIM 1024
#define BATCH       4096
#define TOTAL_ROWS  (NUM_CLASSES * QUEUE_SIZE)   // 25600
#define EPS         1e-12f

typedef float f32x4 __attribute__((ext_vector_type(4)));

// ---------------------------------------------------------------------------
// Kernel 1: direct inverse-map construction, one block per class, 4 waves.
// Pass 1: wave w counts occurrences of class c in labels[w*1024,(w+1)*1024).
// Pass 2: wave w re-scans, writing ordered occurrence list occ[] at its
//         prefix offset (ballot + popc within wave preserves batch order).
// Then thread s (slot index) computes in closed form the LAST occurrence
// landing on slot s (serial FIFO, last-write-wins):
//   k0 = (s - ptr[c]) mod 256 ; valid iff k0 < cnt
//   k  = k0 + 256*floor((cnt-1-k0)/256)
//   inv[c*256+s] = occ[k]  (or -1 if untouched)
// Every inv entry written exactly once: no memset, no atomics, 2-node graph.
// ---------------------------------------------------------------------------
__global__ __launch_bounds__(256) void slots_direct_kernel(
    const int* __restrict__ labels,
    const int* __restrict__ queue_ptr,
    int* __restrict__ inv)
{
    __shared__ int occ[BATCH];     // 16 KB
    __shared__ int wcnt[4];

    const int c    = blockIdx.x;
    const int tid  = threadIdx.x;
    const int lane = tid & 63;
    const int wave = tid >> 6;
    const unsigned long long lt = (1ULL << lane) - 1ULL;

    // pass 1: count
    int cnt_w = 0;
    #pragma unroll 4
    for (int i = 0; i < 16; ++i) {
        const int b = wave * 1024 + i * 64 + lane;
        const unsigned long long mask = __ballot(labels[b] == c);
        cnt_w += __popcll(mask);
    }
    if (lane == 0) wcnt[wave] = cnt_w;
    __syncthreads();

    int off = 0;
    #pragma unroll
    for (int w = 0; w < 4; ++w) off += (w < wave) ? wcnt[w] : 0;
    const int cnt = wcnt[0] + wcnt[1] + wcnt[2] + wcnt[3];

    // pass 2: ordered write of occurrence list
    #pragma unroll 4
    for (int i = 0; i < 16; ++i) {
        const int b = wave * 1024 + i * 64 + lane;
        const bool m = (labels[b] == c);
        const unsigned long long mask = __ballot(m);
        if (m) occ[off + __popcll(mask & lt)] = b;
        off += __popcll(mask);
    }
    __syncthreads();

    // closed-form inverse map
    const int p  = queue_ptr[c] & (QUEUE_SIZE - 1);
    const int s  = tid;
    const int k0 = (s - p) & (QUEUE_SIZE - 1);
    int b = -1;
    if (k0 < cnt) {
        const int k = k0 + (((cnt - 1 - k0) >> 8) << 8);   // last wrap wins
        b = occ[k];
    }
    inv[c * QUEUE_SIZE + s] = b;
}

// ---------------------------------------------------------------------------
// Kernel 2: fused per-row writer (R3's best-measured version, verbatim).
// One 256-thread block per queue row.
//   inv[row] >= 0  -> normalize embedding row inv[row], write it
//   inv[row] <  0  -> stream-copy queue row (nontemporal)
// nt stores mandatory (write stream can't be cached; avoids RFO).
// ---------------------------------------------------------------------------
__global__ __launch_bounds__(256) void fused_write_kernel(
    const float* __restrict__ queue,
    const float* __restrict__ emb,
    const int* __restrict__ inv,
    float* __restrict__ out)
{
    const int row = blockIdx.x;
    const int tid = threadIdx.x;
    const long base = (long)row * FEATURE_DIM;

    const int b = inv[row];

    if (b < 0) {
        const f32x4* src = reinterpret_cast<const f32x4*>(queue + base);
        f32x4*       dst = reinterpret_cast<f32x4*>(out + base);
        f32x4 v = __builtin_nontemporal_load(&src[tid]);
        __builtin_nontemporal_store(v, &dst[tid]);
        return;
    }

    const f32x4* src = reinterpret_cast<const f32x4*>(emb + (long)b * FEATURE_DIM);
    f32x4 v = src[tid];

    float ss = v.x * v.x + v.y * v.y + v.z * v.z + v.w * v.w;
    #pragma unroll
    for (int off = 32; off > 0; off >>= 1) {
        ss += __shfl_down(ss, off, 64);
    }

    __shared__ float s_part[4];
    const int lane = tid & 63;
    const int wave = tid >> 6;
    if (lane == 0) s_part[wave] = ss;
    __syncthreads();

    const float total = s_part[0] + s_part[1] + s_part[2] + s_part[3];
    const float inv_n = 1.0f / fmaxf(sqrtf(total), EPS);

    f32x4 o = v * inv_n;

    f32x4* dst = reinterpret_cast<f32x4*>(out + base);
    __builtin_nontemporal_store(o, &dst[tid]);
}

// ---------------------------------------------------------------------------
extern "C" void kernel_launch(void* const* d_in, const int* in_sizes, int n_in,
                              void* d_out, int out_size, void* d_ws, size_t ws_size,
                              hipStream_t stream)
{
    const float* embeddings = (const float*)d_in[0];   // (4096, 1024) f32
    const int*   labels     = (const int*)d_in[1];     // (4096,) int
    const float* queue      = (const float*)d_in[2];   // (100, 256, 1024) f32
    const int*   queue_ptr  = (const int*)d_in[3];     // (100,) int

    float* out = (float*)d_out;                        // (100, 256, 1024) f32
    int*   inv = (int*)d_ws;                           // 25600 ints scratch

    // 1) direct inverse map: one block per class, multi-wave scan, no memset
    slots_direct_kernel<<<NUM_CLASSES, 256, 0, stream>>>(labels, queue_ptr, inv);

    // 2) fused copy/normalize-scatter: one block per queue row
    fused_write_kernel<<<TOTAL_ROWS, 256, 0, stream>>>(queue, embeddings, inv, out);
}

// Round 9
// 40.753 us; speedup vs baseline: 1.3308x; 1.0055x over previous
//
#include <hip/hip_runtime.h>

#define NUM_CLASSES 100
#define QUEUE_SIZE  256
#define FEATURE_DIM 1024
#define BATCH       4096
#define TOTAL_ROWS  (NUM_CLASSES * QUEUE_SIZE)   // 25600
#define EPS         1e-12f

typedef float f32x4 __attribute__((ext_vector_type(4)));
typedef int   i32x4 __attribute__((ext_vector_type(4)));

// ---------------------------------------------------------------------------
// Kernel 1: direct inverse-map construction, one block per class, 4 waves.
// Labels staged in LDS first (4 coalesced int4 loads/thread, one latency
// exposure), then both ballot passes run against LDS (~6 cy reads).
// Pass 1: wave w counts occurrences of class c in its quarter.
// Pass 2: wave w writes the ordered occurrence list occ[] at its prefix.
// Then thread s (slot index) computes in closed form the LAST occurrence
// landing on slot s (serial FIFO, last-write-wins):
//   k0 = (s - ptr[c]) mod 256 ; valid iff k0 < cnt
//   k  = k0 + 256*floor((cnt-1-k0)/256)
//   inv[c*256+s] = occ[k]  (or -1 if untouched)
// Every inv entry written exactly once: no memset, no atomics.
// ---------------------------------------------------------------------------
__global__ __launch_bounds__(256) void slots_direct_kernel(
    const int* __restrict__ labels,
    const int* __restrict__ queue_ptr,
    int* __restrict__ inv)
{
    __shared__ int s_lab[BATCH];   // 16 KB
    __shared__ int occ[BATCH];     // 16 KB
    __shared__ int wcnt[4];

    const int c    = blockIdx.x;
    const int tid  = threadIdx.x;
    const int lane = tid & 63;
    const int wave = tid >> 6;
    const unsigned long long lt = (1ULL << lane) - 1ULL;

    // stage labels: 4 x int4 per thread, coalesced, 4 loads in flight
    {
        const i32x4* lab4 = reinterpret_cast<const i32x4*>(labels);
        i32x4* s4 = reinterpret_cast<i32x4*>(s_lab);
        i32x4 t0 = lab4[tid];
        i32x4 t1 = lab4[256 + tid];
        i32x4 t2 = lab4[512 + tid];
        i32x4 t3 = lab4[768 + tid];
        s4[tid]       = t0;
        s4[256 + tid] = t1;
        s4[512 + tid] = t2;
        s4[768 + tid] = t3;
    }
    __syncthreads();

    // pass 1: per-wave count (reads from LDS)
    int cnt_w = 0;
    #pragma unroll 4
    for (int i = 0; i < 16; ++i) {
        const int b = wave * 1024 + i * 64 + lane;
        const unsigned long long mask = __ballot(s_lab[b] == c);
        cnt_w += __popcll(mask);
    }
    if (lane == 0) wcnt[wave] = cnt_w;
    __syncthreads();

    int off = 0;
    #pragma unroll
    for (int w = 0; w < 4; ++w) off += (w < wave) ? wcnt[w] : 0;
    const int cnt = wcnt[0] + wcnt[1] + wcnt[2] + wcnt[3];

    // pass 2: ordered write of occurrence list (reads from LDS)
    #pragma unroll 4
    for (int i = 0; i < 16; ++i) {
        const int b = wave * 1024 + i * 64 + lane;
        const bool m = (s_lab[b] == c);
        const unsigned long long mask = __ballot(m);
        if (m) occ[off + __popcll(mask & lt)] = b;
        off += __popcll(mask);
    }
    __syncthreads();

    // closed-form inverse map
    const int p  = queue_ptr[c] & (QUEUE_SIZE - 1);
    const int s  = tid;
    const int k0 = (s - p) & (QUEUE_SIZE - 1);
    int b = -1;
    if (k0 < cnt) {
        const int k = k0 + (((cnt - 1 - k0) >> 8) << 8);   // last wrap wins
        b = occ[k];
    }
    inv[c * QUEUE_SIZE + s] = b;
}

// ---------------------------------------------------------------------------
// Kernel 2: fused per-row writer (best-measured R3 version, unchanged).
// One 256-thread block per queue row.
//   inv[row] >= 0  -> normalize embedding row inv[row], write it
//   inv[row] <  0  -> stream-copy queue row (nontemporal)
// nt stores mandatory (write stream can't be cached; avoids RFO).
// ---------------------------------------------------------------------------
__global__ __launch_bounds__(256) void fused_write_kernel(
    const float* __restrict__ queue,
    const float* __restrict__ emb,
    const int* __restrict__ inv,
    float* __restrict__ out)
{
    const int row = blockIdx.x;
    const int tid = threadIdx.x;
    const long base = (long)row * FEATURE_DIM;

    const int b = inv[row];

    if (b < 0) {
        const f32x4* src = reinterpret_cast<const f32x4*>(queue + base);
        f32x4*       dst = reinterpret_cast<f32x4*>(out + base);
        f32x4 v = __builtin_nontemporal_load(&src[tid]);
        __builtin_nontemporal_store(v, &dst[tid]);
        return;
    }

    const f32x4* src = reinterpret_cast<const f32x4*>(emb + (long)b * FEATURE_DIM);
    f32x4 v = src[tid];

    float ss = v.x * v.x + v.y * v.y + v.z * v.z + v.w * v.w;
    #pragma unroll
    for (int off = 32; off > 0; off >>= 1) {
        ss += __shfl_down(ss, off, 64);
    }

    __shared__ float s_part[4];
    const int lane = tid & 63;
    const int wave = tid >> 6;
    if (lane == 0) s_part[wave] = ss;
    __syncthreads();

    const float total = s_part[0] + s_part[1] + s_part[2] + s_part[3];
    const float inv_n = 1.0f / fmaxf(sqrtf(total), EPS);

    f32x4 o = v * inv_n;

    f32x4* dst = reinterpret_cast<f32x4*>(out + base);
    __builtin_nontemporal_store(o, &dst[tid]);
}

// ---------------------------------------------------------------------------
extern "C" void kernel_launch(void* const* d_in, const int* in_sizes, int n_in,
                              void* d_out, int out_size, void* d_ws, size_t ws_size,
                              hipStream_t stream)
{
    const float* embeddings = (const float*)d_in[0];   // (4096, 1024) f32
    const int*   labels     = (const int*)d_in[1];     // (4096,) int
    const float* queue      = (const float*)d_in[2];   // (100, 256, 1024) f32
    const int*   queue_ptr  = (const int*)d_in[3];     // (100,) int

    float* out = (float*)d_out;                        // (100, 256, 1024) f32
    int*   inv = (int*)d_ws;                           // 25600 ints scratch

    // 1) direct inverse map: one block per class, LDS-staged labels
    slots_direct_kernel<<<NUM_CLASSES, 256, 0, stream>>>(labels, queue_ptr, inv);

    // 2) fused copy/normalize-scatter: one block per queue row
    fused_write_kernel<<<TOTAL_ROWS, 256, 0, stream>>>(queue, embeddings, inv, out);
}